// Round 5
// baseline (59389.343 us; speedup 1.0000x reference)
//
#include <hip/hip_runtime.h>

#define TSTEPS 8192
#define HDIM   1024
#define NLAYER 4
#define NB     256          // 4 groups x 64 blocks, 1 block/CU
#define NT     1024         // 16 waves/block
#define GB     64           // blocks per group (per layer)
#define EPB    16           // h elements per block (1 per wave)
#define RING   8            // ring-buffer depth per layer boundary

typedef float    f32x4 __attribute__((ext_vector_type(4)));
typedef unsigned u32x4 __attribute__((ext_vector_type(4)));

struct GruParams {
  const float* xs;
  const float* Wih[NLAYER];
  const float* Whh[NLAYER];
  const float* bias[NLAYER];
  const float* bn[NLAYER];
  float* out;                   // d_out (written by group 3)
  int*   tags;                  // ws: NB consume-tags (throttle only)
  unsigned long long* hbp;      // ws: NLAYER*2*HDIM (value,epoch) pairs
  unsigned long long* ringp;    // ws: 3*RING*HDIM (value,epoch) pairs
};

__device__ __forceinline__ float sigmoidf_(float x) {
  return 1.0f / (1.0f + __expf(-x));
}
__device__ __forceinline__ float tanhf_(float x) {
  const float e = __expf(2.0f * x);
  return 1.0f - 2.0f / (e + 1.0f);
}
__device__ __forceinline__ float rfl_(float x) {
  return __int_as_float(__builtin_amdgcn_readfirstlane(__float_as_int(x)));
}

// Spin-gather 4 (value,epoch) pairs at pp[0..3] until all epochs == e (sc1,
// IF-coherent); write the 4 values to dst[0..3]. 8B pair stores are atomic,
// so a stale epoch simply means "retry" — no tearing.
__device__ __forceinline__ void gather4_(const unsigned long long* pp,
                                         unsigned e, float* dst) {
  u32x4 A, B;
  for (;;) {
    asm volatile(
        "global_load_dwordx4 %0, %2, off sc1\n\t"
        "global_load_dwordx4 %1, %3, off sc1\n\t"
        "s_waitcnt vmcnt(0)"
        : "=&v"(A), "=&v"(B)
        : "v"(pp), "v"(pp + 2)
        : "memory");
    const bool ok = (A.y == e) & (A.w == e) & (B.y == e) & (B.w == e);
    if (__all(ok)) break;
  }
  dst[0] = __uint_as_float(A.x);
  dst[1] = __uint_as_float(A.z);
  dst[2] = __uint_as_float(B.x);
  dst[3] = __uint_as_float(B.z);
}

__device__ __forceinline__ void store_pair_(unsigned long long* p,
                                            float v, unsigned e) {
  const unsigned long long pk =
      ((unsigned long long)e << 32) | (unsigned long long)__float_as_uint(v);
  asm volatile("global_store_dwordx2 %0, %1, off sc1"
               :: "v"(p), "v"(pk) : "memory");
}

// Layer-pipelined persistent GRU, epoch-tagged dataflow.
// Group g = layer g. Wave w owns h element j = m*16+w (m = member in group),
// with its 6 weight rows (3 ih + 3 hh = 96 floats) register-resident.
// Consumers spin directly on (value,epoch) pairs: one IF propagation per
// dependency instead of store->ack->tag->detect->load.
__global__ __attribute__((amdgpu_waves_per_eu(4, 4)))
__launch_bounds__(NT) void gru_pipe(GruParams p) {
  __shared__ float xst[2][HDIM];
  __shared__ float hst[2][HDIM];
  const int tid  = threadIdx.x;
  const int lane = tid & 63;
  const int wave = tid >> 6;
  const int blk  = blockIdx.x;
  const int g    = blk >> 6;
  const int m    = blk & 63;
  const int j    = m * EPB + wave;

  // ---- weights: 6 rows of 1024 for element j -> 96 VGPRs ----
  const float* Wih = p.Wih[g];
  const float* Whh = p.Whh[g];
  float w[6][16];
#pragma unroll
  for (int dd = 0; dd < 6; ++dd) {
    const float* W = (dd < 3) ? Wih : Whh;
    const int gate = (dd < 3) ? dd : dd - 3;
    const float* src = W + ((size_t)gate * HDIM + j) * HDIM + lane * 4;
#pragma unroll
    for (int i = 0; i < 4; ++i) {
      const f32x4 v = *reinterpret_cast<const f32x4*>(src + i * 256);
      w[dd][i*4+0] = v.x; w[dd][i*4+1] = v.y;
      w[dd][i*4+2] = v.z; w[dd][i*4+3] = v.w;
    }
  }
  const float bb0 = rfl_(p.bias[g][j]);
  const float bb1 = rfl_(p.bias[g][HDIM + j]);
  const float bb2 = rfl_(p.bias[g][2 * HDIM + j]);
  const float bnv = rfl_(p.bn[g][j]);
  float hreg = 0.f;

  unsigned long long* hb = p.hbp + (size_t)g * 2 * HDIM;
  const unsigned long long* ring_in  = p.ringp + (size_t)(g - 1) * RING * HDIM;
  unsigned long long*       ring_out = p.ringp + (size_t)g * RING * HDIM;
  const int* dwnp = p.tags + (g + 1) * GB + lane;   // valid when g<3

  for (int t = 0; t < TSTEPS; ++t) {
    const int ls = t & 1;       // LDS buffer for this tick
    const int base = (wave & 3) * 256 + lane * 4;

    if (wave < 4) {
      // ---- h_{t-1}: pairs in slot t&1 carry epoch t ----
      if (t > 0) {
        gather4_(hb + (size_t)(t & 1) * HDIM + base, (unsigned)t,
                 &hst[ls][base]);
      } else {
        const f32x4 z4 = {0.f, 0.f, 0.f, 0.f};
        *reinterpret_cast<f32x4*>(&hst[ls][base]) = z4;
      }
    } else if (wave < 8) {
      // ---- x_t: ring slot t&7 carries epoch t+1 (layer 0: plain load) ----
      if (g > 0) {
        gather4_(ring_in + (size_t)(t & (RING - 1)) * HDIM + base,
                 (unsigned)(t + 1), &xst[ls][base]);
      } else {
        *reinterpret_cast<f32x4*>(&xst[ls][base]) =
            *reinterpret_cast<const f32x4*>(p.xs + (size_t)t * HDIM + base);
      }
    } else if (wave == 15) {
      // ---- ring-overwrite throttle (off critical path; rarely binds) ----
      if (g < 3 && t >= RING) {
        for (;;) {
          const int v = __hip_atomic_load(dwnp, __ATOMIC_RELAXED,
                                          __HIP_MEMORY_SCOPE_AGENT);
          if (__all(v >= t - (RING - 1))) break;
        }
      }
    }
    __syncthreads();

    // consume-tag: inputs of tick t are now in LDS; upstream may overwrite.
    if (tid == 0)
      __hip_atomic_store(&p.tags[blk], t + 1,
                         __ATOMIC_RELAXED, __HIP_MEMORY_SCOPE_AGENT);

    // ---- 6 dot-1024s (3 ih + 3 hh) ----
    float a0 = 0.f, a1 = 0.f, a2 = 0.f, a3 = 0.f, a4 = 0.f, a5 = 0.f;
#pragma unroll
    for (int i = 0; i < 4; ++i) {
      const f32x4 xc = *reinterpret_cast<const f32x4*>(&xst[ls][lane * 4 + i * 256]);
      const f32x4 hc = *reinterpret_cast<const f32x4*>(&hst[ls][lane * 4 + i * 256]);
#pragma unroll
      for (int q = 0; q < 4; ++q) {
        const float xq = xc[q], hq = hc[q];
        a0 = fmaf(w[0][i*4+q], xq, a0);
        a1 = fmaf(w[1][i*4+q], xq, a1);
        a2 = fmaf(w[2][i*4+q], xq, a2);
        a3 = fmaf(w[3][i*4+q], hq, a3);
        a4 = fmaf(w[4][i*4+q], hq, a4);
        a5 = fmaf(w[5][i*4+q], hq, a5);
      }
    }
#pragma unroll
    for (int off = 32; off > 0; off >>= 1) {
      a0 += __shfl_xor(a0, off, 64);
      a1 += __shfl_xor(a1, off, 64);
      a2 += __shfl_xor(a2, off, 64);
      a3 += __shfl_xor(a3, off, 64);
      a4 += __shfl_xor(a4, off, 64);
      a5 += __shfl_xor(a5, off, 64);
    }

    // ---- gates; publish epoch-tagged h + ring/out ----
    const float r = sigmoidf_(a0 + bb0 + a3);
    const float z = sigmoidf_(a1 + bb1 + a4);
    const float n = tanhf_(a2 + bb2 + r * (a5 + bnv));
    const float hnew = n + z * (hreg - n);
    hreg = hnew;
    if (lane == 0) {
      store_pair_(&hb[(size_t)((t + 1) & 1) * HDIM + j], hnew,
                  (unsigned)(t + 1));
      if (g < 3)
        store_pair_(&ring_out[(size_t)(t & (RING - 1)) * HDIM + j], hnew,
                    (unsigned)(t + 1));
      else
        __hip_atomic_store(&p.out[(size_t)t * HDIM + j], hnew,
                           __ATOMIC_RELAXED, __HIP_MEMORY_SCOPE_AGENT);
    }
    // no end-of-tick barrier: LDS is double-buffered, and epoch checks
    // make early overwrites impossible (a wave can only reach tick t+1's
    // gather after every element's tick-t store, which follows its LDS reads)
  }
}

extern "C" void kernel_launch(void* const* d_in, const int* in_sizes, int n_in,
                              void* d_out, int out_size, void* d_ws, size_t ws_size,
                              hipStream_t stream) {
  GruParams p;
  p.xs = (const float*)d_in[0];
  for (int l = 0; l < NLAYER; ++l) {
    p.Wih[l]  = (const float*)d_in[1 + 4 * l];
    p.Whh[l]  = (const float*)d_in[2 + 4 * l];
    p.bias[l] = (const float*)d_in[3 + 4 * l];
    p.bn[l]   = (const float*)d_in[4 + 4 * l];
  }
  char* ws = (char*)d_ws;
  size_t off = 0;
  p.tags = (int*)(ws + off);
  off += (size_t)NB * sizeof(int);
  off = (off + 255) & ~(size_t)255;
  p.hbp = (unsigned long long*)(ws + off);
  const size_t hbp_bytes = (size_t)NLAYER * 2 * HDIM * 8;
  off += hbp_bytes;
  p.ringp = (unsigned long long*)(ws + off);
  const size_t ring_bytes = (size_t)3 * RING * HDIM * 8;
  off += ring_bytes;
  p.out = (float*)d_out;

  // clear tags + all epoch-bearing pairs (replay safety: epochs restart at 1)
  (void)hipMemsetAsync(p.tags, 0, (size_t)NB * sizeof(int), stream);
  (void)hipMemsetAsync(p.hbp, 0, hbp_bytes, stream);
  (void)hipMemsetAsync(p.ringp, 0, ring_bytes, stream);
  gru_pipe<<<dim3(NB), dim3(NT), 0, stream>>>(p);
}